// Round 14
// baseline (291.185 us; speedup 1.0000x reference)
//
#include <hip/hip_runtime.h>
#include <hip/hip_fp16.h>

// GCN 2-layer. Pipeline (8 launches):
//   blkhist -> rowscan(+fused topscan via last-block) -> scatter2 -> bsort
//   -> gemm1 -> agg1 -> gemm2 -> agg2
// R11 post-mortem: agg1+gemm2 fusion lost to the inter-phase barrier (block
// waits on max-of-16 degrees; 65 us vs 50.6+10 split) -- reverted. This
// round widens gathers to 16 B/lane uint4: agg1 = 8 nodes/wave x 8 lanes,
// agg2 = 16 nodes/wave x 4 lanes; 4-edge unroll -> ~32 outstanding rows per
// wave (attacks the R8 latency-bound profile: 42% fabric BW, 29% VALU).
// R12/R13: container infra failures, no data -- resubmitting unchanged
// (bounds re-audited: all indices within buffer sizes; ws ~46 MB).

#define BSHIFT 8
#define BNODES 256
#define NB 256       // partition blocks
#define BSTRIDE 512  // blkcnt row stride

union H8 {  // 8 fp16 = 16 B (static-index use only! R6 lesson)
    uint4 u;
    __half2 h[4];
};

// Per-block bucket histogram: blkcnt[blk*BSTRIDE + bin]. Also zeroes done.
__global__ __launch_bounds__(256) void blkhist_kernel(
    const int* __restrict__ dst, int E, int* __restrict__ blkcnt,
    int* __restrict__ done, int B) {
    __shared__ int h[512];
    int t = threadIdx.x, b = blockIdx.x;
    if (b == 0 && t == 0) *done = 0;
    for (int i = t; i < 512; i += 256) h[i] = 0;
    __syncthreads();
    int per = (E + NB - 1) / NB;
    int lo = b * per;
    int hi = min(lo + per, E);
    for (int i = lo + t; i < hi; i += 256) atomicAdd(&h[dst[i] >> BSHIFT], 1);
    __syncthreads();
    for (int i = t; i < B; i += 256) blkcnt[b * BSTRIDE + i] = h[i];
}

// One block per bin: exclusive scan across NB block counts (in place), emit
// bin total. The LAST block to finish also scans bin totals -> base[].
__global__ __launch_bounds__(256) void rowscan_kernel(
    int* __restrict__ blkcnt, int* __restrict__ rowtot, int* __restrict__ base,
    int* __restrict__ off, int* __restrict__ done, int B, int E, int N) {
    __shared__ int s[256];
    __shared__ int isLast;
    int t = threadIdx.x, bin = blockIdx.x;
    int v = blkcnt[t * BSTRIDE + bin];
    s[t] = v;
    __syncthreads();
#pragma unroll
    for (int d = 1; d < 256; d <<= 1) {
        int u = (t >= d) ? s[t - d] : 0;
        __syncthreads();
        s[t] += u;
        __syncthreads();
    }
    blkcnt[t * BSTRIDE + bin] = s[t] - v;  // block-exclusive prefix
    if (t == 255) rowtot[bin] = s[255];
    __threadfence();  // release rowtot before signaling
    if (t == 0) isLast = (atomicAdd(done, 1) == gridDim.x - 1);
    __syncthreads();
    if (!isLast) return;
    __threadfence();  // acquire other blocks' rowtot
    int a0 = (t < B) ? rowtot[t] : 0;
    int a1 = (t + 256 < B) ? rowtot[t + 256] : 0;
    __syncthreads();
    s[t] = a0;
    __syncthreads();
#pragma unroll
    for (int d = 1; d < 256; d <<= 1) {
        int u = (t >= d) ? s[t - d] : 0;
        __syncthreads();
        s[t] += u;
        __syncthreads();
    }
    int pA = s[t] - a0;
    int TA = s[255];
    __syncthreads();
    s[t] = a1;
    __syncthreads();
#pragma unroll
    for (int d = 1; d < 256; d <<= 1) {
        int u = (t >= d) ? s[t - d] : 0;
        __syncthreads();
        s[t] += u;
        __syncthreads();
    }
    int pB = s[t] - a1;
    if (t < B) base[t] = pA;
    if (t + 256 < B) base[t + 256] = TA + pB;
    if (t == 0) {
        base[B] = E;
        off[N] = E;
    }
}

// Scatter via LDS cursors seeded from precomputed bases. No global atomics.
__global__ __launch_bounds__(256) void scatter2_kernel(
    const int* __restrict__ src, const int* __restrict__ dst,
    const int* __restrict__ blkcnt, const int* __restrict__ base,
    int* __restrict__ packed, int E, int B) {
    __shared__ int cur[512];
    int t = threadIdx.x, b = blockIdx.x;
    for (int i = t; i < B; i += 256) cur[i] = base[i] + blkcnt[b * BSTRIDE + i];
    __syncthreads();
    int per = (E + NB - 1) / NB;
    int lo = b * per;
    int hi = min(lo + per, E);
    for (int i = lo + t; i < hi; i += 256) {
        int d = dst[i];
        int pos = atomicAdd(&cur[d >> BSHIFT], 1);
        packed[pos] = (src[i] << BSHIFT) | (d & (BNODES - 1));
    }
}

// Per-bucket LDS counting sort -> ssrc grouped by node; also off & dinv.
__global__ __launch_bounds__(256) void bsort_kernel(
    const int* __restrict__ packed, const int* __restrict__ base,
    int* __restrict__ ssrc, int* __restrict__ off, float* __restrict__ dinv,
    int N) {
    __shared__ int s[BNODES];
    __shared__ int cur[BNODES];
    int t = threadIdx.x, b = blockIdx.x;
    s[t] = 0;
    __syncthreads();
    int lo = base[b], hi = base[b + 1];
    for (int i = lo + t; i < hi; i += 256)
        atomicAdd(&s[packed[i] & (BNODES - 1)], 1);
    __syncthreads();
    int deg = s[t];
    __syncthreads();
    s[t] = deg;
    __syncthreads();
#pragma unroll
    for (int d = 1; d < BNODES; d <<= 1) {
        int v = (t >= d) ? s[t - d] : 0;
        __syncthreads();
        s[t] += v;
        __syncthreads();
    }
    int excl = s[t] - deg;
    cur[t] = excl;
    int node = (b << BSHIFT) + t;
    if (node < N) {
        off[node] = lo + excl;
        dinv[node] = rsqrtf((float)(deg + 1));
    }
    __syncthreads();
    for (int i = lo + t; i < hi; i += 256) {
        int p = packed[i];
        int pos = atomicAdd(&cur[p & (BNODES - 1)], 1);
        ssrc[lo + pos] = p >> BSHIFT;
    }
}

// hsh = fp16((x@W1)*dinv). 2 rows/thread, W1 broadcast from LDS.
__global__ __launch_bounds__(256) void gemm1_kernel(
    const float* __restrict__ x, const float* __restrict__ W1,
    const float* __restrict__ dinv, __half* __restrict__ hsh, int N) {
    __shared__ float4 Ws[64 * 16];
    int t = threadIdx.x;
    const float4* W4 = (const float4*)W1;
    for (int i = t; i < 1024; i += 256) Ws[i] = W4[i];
    __syncthreads();
    int ra = blockIdx.x * 512 + t;
    int rb = ra + 256;
    if (ra >= N) return;
    bool hb = rb < N;
    const float4* xa = (const float4*)(x + (size_t)ra * 64);
    const float4* xb = (const float4*)(x + (size_t)rb * 64);
    float4 acc0[16], acc1[16];
#pragma unroll
    for (int j = 0; j < 16; j++) {
        acc0[j] = make_float4(0.f, 0.f, 0.f, 0.f);
        acc1[j] = make_float4(0.f, 0.f, 0.f, 0.f);
    }
    for (int k4 = 0; k4 < 16; k4++) {
        float4 x0 = xa[k4];
        float4 x1 = hb ? xb[k4] : make_float4(0.f, 0.f, 0.f, 0.f);
#pragma unroll
        for (int kk = 0; kk < 4; kk++) {
            float a0 = ((const float*)&x0)[kk];
            float a1 = ((const float*)&x1)[kk];
            const float4* wr = &Ws[(k4 * 4 + kk) * 16];
#pragma unroll
            for (int j = 0; j < 16; j++) {
                float4 w = wr[j];
                acc0[j].x += a0 * w.x; acc0[j].y += a0 * w.y;
                acc0[j].z += a0 * w.z; acc0[j].w += a0 * w.w;
                acc1[j].x += a1 * w.x; acc1[j].y += a1 * w.y;
                acc1[j].z += a1 * w.z; acc1[j].w += a1 * w.w;
            }
        }
    }
    float d0 = dinv[ra];
    uint4* ha = (uint4*)(hsh + (size_t)ra * 64);
#pragma unroll
    for (int j = 0; j < 8; j++) {
        H8 p;
        float4 v0 = acc0[2 * j], v1 = acc0[2 * j + 1];
        p.h[0] = __floats2half2_rn(v0.x * d0, v0.y * d0);
        p.h[1] = __floats2half2_rn(v0.z * d0, v0.w * d0);
        p.h[2] = __floats2half2_rn(v1.x * d0, v1.y * d0);
        p.h[3] = __floats2half2_rn(v1.z * d0, v1.w * d0);
        ha[j] = p.u;
    }
    if (hb) {
        float d1 = dinv[rb];
        uint4* hbp = (uint4*)(hsh + (size_t)rb * 64);
#pragma unroll
        for (int j = 0; j < 8; j++) {
            H8 p;
            float4 v0 = acc1[2 * j], v1 = acc1[2 * j + 1];
            p.h[0] = __floats2half2_rn(v0.x * d1, v0.y * d1);
            p.h[1] = __floats2half2_rn(v0.z * d1, v0.w * d1);
            p.h[2] = __floats2half2_rn(v1.x * d1, v1.y * d1);
            p.h[3] = __floats2half2_rn(v1.z * d1, v1.w * d1);
            hbp[j] = p.u;
        }
    }
}

#define ADD8(A0, A1, A2, A3, V)                                   \
    {                                                             \
        float2 f_;                                                \
        f_ = __half22float2((V).h[0]); A0.x += f_.x; A0.y += f_.y;\
        f_ = __half22float2((V).h[1]); A1.x += f_.x; A1.y += f_.y;\
        f_ = __half22float2((V).h[2]); A2.x += f_.x; A2.y += f_.y;\
        f_ = __half22float2((V).h[3]); A3.x += f_.x; A3.y += f_.y;\
    }

// Layer-1 aggregate: 8 nodes/wave, 8 lanes/node, 16 B/lane (uint4 = 8 fp16).
// 4-edge unroll -> up to 32 outstanding 128 B rows per wave.
__global__ __launch_bounds__(256) void agg1_kernel(
    const uint4* __restrict__ hs8, const int* __restrict__ ssrc,
    const int* __restrict__ off, const float* __restrict__ dinv,
    const float* __restrict__ b1, uint4* __restrict__ h18, int N) {
    int lane = threadIdx.x & 63;
    int wid = (blockIdx.x * 256 + threadIdx.x) >> 6;
    int node = wid * 8 + (lane >> 3);
    int fq = lane & 7;  // feats 8*fq .. 8*fq+7
    if (node >= N) return;
    H8 s;
    s.u = hs8[(size_t)node * 8 + fq];  // self-loop
    float2 a0 = __half22float2(s.h[0]), a1 = __half22float2(s.h[1]);
    float2 a2 = __half22float2(s.h[2]), a3 = __half22float2(s.h[3]);
    float2 c0 = {0.f, 0.f}, c1 = {0.f, 0.f}, c2 = {0.f, 0.f}, c3 = {0.f, 0.f};
    int lo = off[node], hi = off[node + 1];
    int e = lo;
    for (; e + 4 <= hi; e += 4) {
        int i0 = ssrc[e], i1 = ssrc[e + 1], i2 = ssrc[e + 2], i3 = ssrc[e + 3];
        H8 v0, v1, v2, v3;
        v0.u = hs8[(size_t)i0 * 8 + fq];
        v1.u = hs8[(size_t)i1 * 8 + fq];
        v2.u = hs8[(size_t)i2 * 8 + fq];
        v3.u = hs8[(size_t)i3 * 8 + fq];
        ADD8(a0, a1, a2, a3, v0);
        ADD8(c0, c1, c2, c3, v1);
        ADD8(a0, a1, a2, a3, v2);
        ADD8(c0, c1, c2, c3, v3);
    }
    for (; e < hi; e++) {
        H8 v;
        v.u = hs8[(size_t)ssrc[e] * 8 + fq];
        ADD8(a0, a1, a2, a3, v);
    }
    float di = dinv[node];
    float4 bA = ((const float4*)b1)[2 * fq];
    float4 bB = ((const float4*)b1)[2 * fq + 1];
    float r0 = fmaxf((a0.x + c0.x) * di + bA.x, 0.f);
    float r1 = fmaxf((a0.y + c0.y) * di + bA.y, 0.f);
    float r2 = fmaxf((a1.x + c1.x) * di + bA.z, 0.f);
    float r3 = fmaxf((a1.y + c1.y) * di + bA.w, 0.f);
    float r4 = fmaxf((a2.x + c2.x) * di + bB.x, 0.f);
    float r5 = fmaxf((a2.y + c2.y) * di + bB.y, 0.f);
    float r6 = fmaxf((a3.x + c3.x) * di + bB.z, 0.f);
    float r7 = fmaxf((a3.y + c3.y) * di + bB.w, 0.f);
    H8 o;
    o.h[0] = __floats2half2_rn(r0, r1);
    o.h[1] = __floats2half2_rn(r2, r3);
    o.h[2] = __floats2half2_rn(r4, r5);
    o.h[3] = __floats2half2_rn(r6, r7);
    h18[(size_t)node * 8 + fq] = o.u;
}

// gsh = fp16((h1@W2)*dinv). One row/thread; direct __half2 loads (R6 lesson).
__global__ __launch_bounds__(256) void gemm2_kernel(
    const __half* __restrict__ h1h, const float* __restrict__ W2,
    const float* __restrict__ dinv, __half* __restrict__ gsh, int N) {
    __shared__ float4 Ws[64 * 8];
    int t = threadIdx.x;
    const float4* W4 = (const float4*)W2;
    for (int i = t; i < 512; i += 256) Ws[i] = W4[i];
    __syncthreads();
    int r = blockIdx.x * 256 + t;
    if (r >= N) return;
    const __half2* xr = (const __half2*)(h1h + (size_t)r * 64);
    float4 acc[8];
#pragma unroll
    for (int j = 0; j < 8; j++) acc[j] = make_float4(0.f, 0.f, 0.f, 0.f);
#pragma unroll
    for (int k2 = 0; k2 < 32; k2++) {
        float2 f = __half22float2(xr[k2]);
        const float4* w0 = &Ws[(2 * k2) * 8];
        const float4* w1 = &Ws[(2 * k2 + 1) * 8];
#pragma unroll
        for (int j = 0; j < 8; j++) {
            float4 wa = w0[j];
            acc[j].x += f.x * wa.x; acc[j].y += f.x * wa.y;
            acc[j].z += f.x * wa.z; acc[j].w += f.x * wa.w;
        }
#pragma unroll
        for (int j = 0; j < 8; j++) {
            float4 wb = w1[j];
            acc[j].x += f.y * wb.x; acc[j].y += f.y * wb.y;
            acc[j].z += f.y * wb.z; acc[j].w += f.y * wb.w;
        }
    }
    float d0 = dinv[r];
    uint4* g = (uint4*)(gsh + (size_t)r * 32);
#pragma unroll
    for (int j = 0; j < 4; j++) {
        H8 p;
        float4 v0 = acc[2 * j], v1 = acc[2 * j + 1];
        p.h[0] = __floats2half2_rn(v0.x * d0, v0.y * d0);
        p.h[1] = __floats2half2_rn(v0.z * d0, v0.w * d0);
        p.h[2] = __floats2half2_rn(v1.x * d0, v1.y * d0);
        p.h[3] = __floats2half2_rn(v1.z * d0, v1.w * d0);
        g[j] = p.u;
    }
}

// Layer-2 aggregate: 16 nodes/wave, 4 lanes/node, 16 B/lane. fp32 out.
__global__ __launch_bounds__(256) void agg2_kernel(
    const uint4* __restrict__ gs8, const int* __restrict__ ssrc,
    const int* __restrict__ off, const float* __restrict__ dinv,
    const float* __restrict__ b2, float* __restrict__ out, int N) {
    int lane = threadIdx.x & 63;
    int wid = (blockIdx.x * 256 + threadIdx.x) >> 6;
    int node = wid * 16 + (lane >> 2);
    int fq = lane & 3;  // feats 8*fq .. 8*fq+7
    if (node >= N) return;
    H8 s;
    s.u = gs8[(size_t)node * 4 + fq];  // self-loop
    float2 a0 = __half22float2(s.h[0]), a1 = __half22float2(s.h[1]);
    float2 a2 = __half22float2(s.h[2]), a3 = __half22float2(s.h[3]);
    float2 c0 = {0.f, 0.f}, c1 = {0.f, 0.f}, c2 = {0.f, 0.f}, c3 = {0.f, 0.f};
    int lo = off[node], hi = off[node + 1];
    int e = lo;
    for (; e + 4 <= hi; e += 4) {
        int i0 = ssrc[e], i1 = ssrc[e + 1], i2 = ssrc[e + 2], i3 = ssrc[e + 3];
        H8 v0, v1, v2, v3;
        v0.u = gs8[(size_t)i0 * 4 + fq];
        v1.u = gs8[(size_t)i1 * 4 + fq];
        v2.u = gs8[(size_t)i2 * 4 + fq];
        v3.u = gs8[(size_t)i3 * 4 + fq];
        ADD8(a0, a1, a2, a3, v0);
        ADD8(c0, c1, c2, c3, v1);
        ADD8(a0, a1, a2, a3, v2);
        ADD8(c0, c1, c2, c3, v3);
    }
    for (; e < hi; e++) {
        H8 v;
        v.u = gs8[(size_t)ssrc[e] * 4 + fq];
        ADD8(a0, a1, a2, a3, v);
    }
    float di = dinv[node];
    float4 bA = ((const float4*)b2)[2 * fq];
    float4 bB = ((const float4*)b2)[2 * fq + 1];
    float4 rA, rB;
    rA.x = (a0.x + c0.x) * di + bA.x;
    rA.y = (a0.y + c0.y) * di + bA.y;
    rA.z = (a1.x + c1.x) * di + bA.z;
    rA.w = (a1.y + c1.y) * di + bA.w;
    rB.x = (a2.x + c2.x) * di + bB.x;
    rB.y = (a2.y + c2.y) * di + bB.y;
    rB.z = (a3.x + c3.x) * di + bB.z;
    rB.w = (a3.y + c3.y) * di + bB.w;
    float4* op = (float4*)(out + (size_t)node * 32 + 8 * fq);
    op[0] = rA;
    op[1] = rB;
}

extern "C" void kernel_launch(void* const* d_in, const int* in_sizes, int n_in,
                              void* d_out, int out_size, void* d_ws,
                              size_t ws_size, hipStream_t stream) {
    const float* x  = (const float*)d_in[0];
    const int* ei   = (const int*)d_in[1];
    const float* W1 = (const float*)d_in[2];
    const float* b1 = (const float*)d_in[3];
    const float* W2 = (const float*)d_in[4];
    const float* b2 = (const float*)d_in[5];
    int N = in_sizes[0] / 64;
    int E = in_sizes[1] / 2;
    const int* src = ei;
    const int* dst = ei + E;
    int B = (N + BNODES - 1) >> BSHIFT;  // 391 for N=100000

    char* ws = (char*)d_ws;
    size_t o = 0;
    auto align16 = [&o]() { o = (o + 15) & ~(size_t)15; };
    int* blkcnt  = (int*)(ws + o); o += (size_t)NB * BSTRIDE * 4; align16();
    int* rowtot  = (int*)(ws + o); o += 512 * 4; align16();
    int* base    = (int*)(ws + o); o += 513 * 4; align16();
    int* done    = (int*)(ws + o); o += 16; align16();
    int* off     = (int*)(ws + o); o += ((size_t)N + 1) * 4; align16();
    float* dinv  = (float*)(ws + o); o += (size_t)N * 4; align16();
    int* packed  = (int*)(ws + o); o += (size_t)E * 4; align16();
    int* ssrc    = (int*)(ws + o); o += (size_t)E * 4; align16();
    __half* hsh  = (__half*)(ws + o); o += (size_t)N * 64 * 2; align16();
    __half* h1h  = (__half*)(ws + o); o += (size_t)N * 64 * 2; align16();
    __half* gsh  = (__half*)(ws + o); o += (size_t)N * 32 * 2; align16();
    float* outp  = (float*)d_out;

    blkhist_kernel<<<NB, 256, 0, stream>>>(dst, E, blkcnt, done, B);
    rowscan_kernel<<<B, 256, 0, stream>>>(blkcnt, rowtot, base, off, done, B,
                                          E, N);
    scatter2_kernel<<<NB, 256, 0, stream>>>(src, dst, blkcnt, base, packed, E,
                                            B);
    bsort_kernel<<<B, 256, 0, stream>>>(packed, base, ssrc, off, dinv, N);
    gemm1_kernel<<<(N + 511) / 512, 256, 0, stream>>>(x, W1, dinv, hsh, N);
    int g1 = (int)(((size_t)((N + 7) / 8) * 64 + 255) / 256);
    agg1_kernel<<<g1, 256, 0, stream>>>((const uint4*)hsh, ssrc, off, dinv, b1,
                                        (uint4*)h1h, N);
    gemm2_kernel<<<(N + 255) / 256, 256, 0, stream>>>(h1h, W2, dinv, gsh, N);
    int g2 = (int)(((size_t)((N + 15) / 16) * 64 + 255) / 256);
    agg2_kernel<<<g2, 256, 0, stream>>>((const uint4*)gsh, ssrc, off, dinv, b2,
                                        outp, N);
}